// Round 9
// baseline (120.262 us; speedup 1.0000x reference)
//
#include <hip/hip_runtime.h>
#include <stdint.h>

// Problem constants (fixed by setup_inputs)
#define TOKENS 64
#define IN_F   4096
#define OUT_F  11008
#define RANK   16
#define GS     128
#define NG     32
#define ZCOLS  (OUT_F / 8)
#define LORA_SCALE 2.0f
#define KSEG 4                // split-K segments
#define GPK  (NG / KSEG)      // groups per kseg = 8

using short8  = __attribute__((ext_vector_type(8))) short;
using float4v = __attribute__((ext_vector_type(4))) float;

// round-to-nearest-even fp32 -> bf16 bits; also returns the rounded-back fp32
static __device__ inline uint16_t f2bf(float f, float* back) {
    uint32_t u = __float_as_uint(f);
    uint32_t r = (u + 0x7FFFu + ((u >> 16) & 1u)) >> 16;
    *back = __uint_as_float(r << 16);
    return (uint16_t)r;
}

// ---------------------------------------------------------------------------
// K1: per token t (64 blocks):
//   xf (MFMA-fragment order) = bf16(x)  — xf4[(mt*128 + kchunk)*64 + quad*16 + n]
//   xsumT[g][t] = sum over group g of bf16-rounded x   (GPTQ zero fold)
//   midT[j][t]  = sum_k x[t][k] * lora_A[j][k]         (fp32 LoRA mid)
// ---------------------------------------------------------------------------
__global__ __launch_bounds__(256) void prep_kernel(
        const float* __restrict__ x,
        const float* __restrict__ loraA,
        uint4* __restrict__ xf4,
        float* __restrict__ xsumT,
        float* __restrict__ midT) {
    __shared__ float redg[256];
    __shared__ float redm[4][16];
    const int t    = blockIdx.x;
    const int tid  = threadIdx.x;
    const int lane = tid & 63;
    const int wv   = tid >> 6;

    float4 xv[4];
    const float4* xp = (const float4*)(x + (size_t)t * IN_F + tid * 16);
    #pragma unroll
    for (int i = 0; i < 4; ++i) xv[i] = xp[i];

    union { uint16_t u[16]; uint4 q[2]; } ob;
    float s = 0.f;
    #pragma unroll
    for (int i = 0; i < 4; ++i) {
        float b;
        ob.u[i * 4 + 0] = f2bf(xv[i].x, &b); s += b;
        ob.u[i * 4 + 1] = f2bf(xv[i].y, &b); s += b;
        ob.u[i * 4 + 2] = f2bf(xv[i].z, &b); s += b;
        ob.u[i * 4 + 3] = f2bf(xv[i].w, &b); s += b;
    }
    // scatter into fragment order
    {
        const int mm = t >> 4, nn = t & 15;
        const int kchunk = tid >> 1;
        #pragma unroll
        for (int i = 0; i < 2; ++i) {
            const int qd = (tid * 2 + i) & 3;
            xf4[(size_t)((mm * 128 + kchunk) * 64 + qd * 16 + nn)] = ob.q[i];
        }
    }
    redg[tid] = s;

    // LoRA mid partials
    float pj[16];
    #pragma unroll
    for (int j = 0; j < 16; ++j) {
        const float4* ap = (const float4*)(loraA + (size_t)j * IN_F + tid * 16);
        float ps = 0.f;
        #pragma unroll
        for (int i = 0; i < 4; ++i) {
            float4 a = ap[i];
            ps += a.x * xv[i].x + a.y * xv[i].y + a.z * xv[i].z + a.w * xv[i].w;
        }
        pj[j] = ps;
    }
    #pragma unroll
    for (int j = 0; j < 16; ++j) {
        #pragma unroll
        for (int off = 32; off; off >>= 1) pj[j] += __shfl_down(pj[j], off);
    }
    if (lane == 0) {
        #pragma unroll
        for (int j = 0; j < 16; ++j) redm[wv][j] = pj[j];
    }
    __syncthreads();
    if (tid < NG) {
        float g = 0.f;
        #pragma unroll
        for (int i = 0; i < 8; ++i) g += redg[tid * 8 + i];
        xsumT[tid * TOKENS + t] = g;
    }
    if (tid < 16)
        midT[tid * TOKENS + t] = redm[0][tid] + redm[1][tid] + redm[2][tid] + redm[3][tid];
}

// ---------------------------------------------------------------------------
// K2: GPTQ-dequant GEMM, split-K=4 to ws partials, zero LDS / zero barriers /
// zero atomics. Grid = 344 col-slices x 4 ksegs; block 256 = 4 waves = 4
// M-tiles (same cols, same kseg -> B loads identical across waves, L1-shared).
// Wave = 1 M-tile x 32 cols x 8 groups. Depth-2 rings; B (HBM) issued first.
// Dequant via 0x4300 trick (bf16(128+q)); per-group fold removes
// (zero+1+128)*xsum and applies scale. Partials stored plain & coalesced.
// ---------------------------------------------------------------------------
#define LOADG(st, g) do {                                                       \
    _Pragma("unroll")                                                           \
    for (int ks = 0; ks < 4; ++ks)                                              \
        _Pragma("unroll")                                                       \
        for (int nh = 0; nh < 2; ++nh)                                          \
            B[st][ks * 2 + nh] =                                                \
                qwc[(size_t)((g) * 16 + ks * 4 + quad) * OUT_F + nh * 16];      \
    _Pragma("unroll")                                                           \
    for (int ks = 0; ks < 4; ++ks)                                              \
        A[st][ks] = xf4[(size_t)((m * 128 + (g) * 4 + ks) * 64) + lane];        \
    XS[st] = *(const float4*)(xsumT + (g) * 64 + m * 16 + quad * 4);            \
    _Pragma("unroll")                                                           \
    for (int nh = 0; nh < 2; ++nh) {                                            \
        S[st][nh] = scales[(size_t)(g) * OUT_F + col0 + nh * 16 + n];           \
        Z[st][nh] = qz[(size_t)(g) * ZCOLS + ((col0 + nh * 16 + n) >> 3)];      \
    }                                                                           \
} while (0)

#define COMPUTEG(st) do {                                                       \
    float4v accg[2];                                                            \
    accg[0] = (float4v){0.f, 0.f, 0.f, 0.f};                                    \
    accg[1] = (float4v){0.f, 0.f, 0.f, 0.f};                                    \
    _Pragma("unroll")                                                           \
    for (int ks = 0; ks < 4; ++ks) {                                            \
        union { uint4 u; short8 s; } afu; afu.u = A[st][ks];                    \
        _Pragma("unroll")                                                       \
        for (int nh = 0; nh < 2; ++nh) {                                        \
            uint32_t q  = B[st][ks * 2 + nh];                                   \
            uint32_t lo = q & 0x0F0F0F0Fu;                                      \
            uint32_t hi = (q >> 4) & 0x0F0F0F0Fu;                               \
            union { uint32_t u32[4]; short8 s8; } bf;                           \
            _Pragma("unroll")                                                   \
            for (int i = 0; i < 4; ++i)                                         \
                bf.u32[i] = __builtin_amdgcn_perm(hi, lo,                       \
                                0x0C040C00u + i * 0x00010001u) | 0x43004300u;   \
            accg[nh] = __builtin_amdgcn_mfma_f32_16x16x32_bf16(afu.s, bf.s8,    \
                                                            accg[nh], 0, 0, 0); \
        }                                                                       \
    }                                                                           \
    const float xr[4] = {XS[st].x, XS[st].y, XS[st].z, XS[st].w};               \
    _Pragma("unroll")                                                           \
    for (int nh = 0; nh < 2; ++nh) {                                            \
        const float zoff = (float)(((Z[st][nh] >>                               \
                        (((col0 + nh * 16 + n) & 7) * 4)) & 0xFu) + 129u);      \
        const float scl = S[st][nh];                                            \
        _Pragma("unroll")                                                       \
        for (int r = 0; r < 4; ++r)                                             \
            acc[nh][r] = fmaf(scl, fmaf(-zoff, xr[r], accg[nh][r]),             \
                              acc[nh][r]);                                      \
    }                                                                           \
} while (0)

__global__ __launch_bounds__(256, 5) void main_kernel(
        const uint32_t* __restrict__ qw,
        const uint32_t* __restrict__ qz,
        const float* __restrict__ scales,
        const uint4* __restrict__ xf4,
        const float* __restrict__ xsumT,
        float* __restrict__ part) {
    const int tid  = threadIdx.x;
    const int m    = tid >> 6;             // wave = M-tile 0..3
    const int lane = tid & 63;
    const int n    = lane & 15;
    const int quad = lane >> 4;
    const int cs   = blockIdx.x >> 2;      // col-slice
    const int kseg = blockIdx.x & 3;
    const int col0 = cs * 32;
    const int g0   = kseg * GPK;

    const uint32_t* qwc = qw + col0 + n;

    float4v acc[2];
    acc[0] = (float4v){0.f, 0.f, 0.f, 0.f};
    acc[1] = (float4v){0.f, 0.f, 0.f, 0.f};

    uint4    A[2][4];
    uint32_t B[2][8];
    float4   XS[2];
    float    S[2][2];
    uint32_t Z[2][2];

    LOADG(0, g0);
    LOADG(1, g0 + 1);
    #pragma unroll
    for (int gi = 0; gi < GPK; ++gi) {
        const int st = gi & 1;
        COMPUTEG(st);
        if (gi + 2 < GPK) LOADG(st, g0 + gi + 2);   // folds at compile time
    }

    // plain coalesced partial stores: part[kseg][t][col]
    float* pp = part + (size_t)kseg * TOKENS * OUT_F;
    #pragma unroll
    for (int nh = 0; nh < 2; ++nh)
        #pragma unroll
        for (int r = 0; r < 4; ++r) {
            const int t = m * 16 + quad * 4 + r;
            pp[(size_t)t * OUT_F + col0 + nh * 16 + n] = acc[nh][r];
        }
}

// ---------------------------------------------------------------------------
// K3: combine split-K partials + LoRA: out[t][o] = sum_ks part[ks][t][o]
//                                               + 2 * sum_j midT[j][t]*loraB[o][j]
// Each block spans 256 consecutive o within one t -> midT reads wave-uniform.
// ---------------------------------------------------------------------------
__global__ __launch_bounds__(256) void combine_kernel(
        const float* __restrict__ part,
        const float* __restrict__ midT,
        const float* __restrict__ loraB,
        float* __restrict__ out) {
    const int gid = blockIdx.x * 256 + threadIdx.x;
    const int t = gid / OUT_F;
    const int o = gid - t * OUT_F;

    float s = 0.f;
    #pragma unroll
    for (int ks = 0; ks < KSEG; ++ks)
        s += part[(size_t)ks * TOKENS * OUT_F + gid];

    const float4* b4 = (const float4*)(loraB + (size_t)o * RANK);
    float ls = 0.f;
    #pragma unroll
    for (int i = 0; i < 4; ++i) {
        float4 b = b4[i];
        ls += b.x * midT[(i * 4 + 0) * TOKENS + t];
        ls += b.y * midT[(i * 4 + 1) * TOKENS + t];
        ls += b.z * midT[(i * 4 + 2) * TOKENS + t];
        ls += b.w * midT[(i * 4 + 3) * TOKENS + t];
    }
    out[gid] = s + LORA_SCALE * ls;
}

// ---------------------------------------------------------------------------
extern "C" void kernel_launch(void* const* d_in, const int* in_sizes, int n_in,
                              void* d_out, int out_size, void* d_ws, size_t ws_size,
                              hipStream_t stream) {
    const float*    x      = (const float*)d_in[0];
    const uint32_t* qw     = (const uint32_t*)d_in[1];
    const uint32_t* qz     = (const uint32_t*)d_in[2];
    const float*    scales = (const float*)d_in[3];
    const float*    loraA  = (const float*)d_in[4];
    const float*    loraB  = (const float*)d_in[5];
    float* out = (float*)d_out;

    // ws layout: xf [4][128][64] uint4 (512 KB) | xsumT [32][64] | midT [16][64]
    //            | part [4][64][11008] f32 (11.3 MB)
    uint4* xf4   = (uint4*)d_ws;
    float* xsumT = (float*)((char*)d_ws + (size_t)TOKENS * IN_F * 2);
    float* midT  = xsumT + NG * TOKENS;
    float* part  = midT + RANK * TOKENS;

    prep_kernel<<<TOKENS, 256, 0, stream>>>(x, loraA, xf4, xsumT, midT);
    main_kernel<<<(OUT_F / 32) * KSEG, 256, 0, stream>>>(qw, qz, scales, xf4, xsumT, part);
    combine_kernel<<<(TOKENS * OUT_F) / 256, 256, 0, stream>>>(part, midT, loraB, out);
}

// Round 10
// 118.831 us; speedup vs baseline: 1.0120x; 1.0120x over previous
//
#include <hip/hip_runtime.h>
#include <stdint.h>

// Problem constants (fixed by setup_inputs)
#define TOKENS 64
#define IN_F   4096
#define OUT_F  11008
#define RANK   16
#define GS     128
#define NG     32
#define ZCOLS  (OUT_F / 8)
#define LORA_SCALE 2.0f
#define GPK 8                 // groups per kseg (NG / 4)

using short8  = __attribute__((ext_vector_type(8))) short;
using float4v = __attribute__((ext_vector_type(4))) float;

// round-to-nearest-even fp32 -> bf16 bits; also returns the rounded-back fp32
static __device__ inline uint16_t f2bf(float f, float* back) {
    uint32_t u = __float_as_uint(f);
    uint32_t r = (u + 0x7FFFu + ((u >> 16) & 1u)) >> 16;
    *back = __uint_as_float(r << 16);
    return (uint16_t)r;
}

// ---------------------------------------------------------------------------
// K1: per token t (64 blocks):
//   xf (MFMA-fragment order) = bf16(x)  — xf4[(mt*128 + kchunk)*64 + quad*16 + n]
//   xsumT[g][t] = sum over group g of bf16-rounded x   (GPTQ zero fold)
//   midT[j][t]  = sum_k x[t][k] * lora_A[j][k]         (fp32 LoRA mid)
// ---------------------------------------------------------------------------
__global__ __launch_bounds__(256) void prep_kernel(
        const float* __restrict__ x,
        const float* __restrict__ loraA,
        uint4* __restrict__ xf4,
        float* __restrict__ xsumT,
        float* __restrict__ midT) {
    __shared__ float redg[256];
    __shared__ float redm[4][16];
    const int t    = blockIdx.x;
    const int tid  = threadIdx.x;
    const int lane = tid & 63;
    const int wv   = tid >> 6;

    float4 xv[4];
    const float4* xp = (const float4*)(x + (size_t)t * IN_F + tid * 16);
    #pragma unroll
    for (int i = 0; i < 4; ++i) xv[i] = xp[i];

    union { uint16_t u[16]; uint4 q[2]; } ob;
    float s = 0.f;
    #pragma unroll
    for (int i = 0; i < 4; ++i) {
        float b;
        ob.u[i * 4 + 0] = f2bf(xv[i].x, &b); s += b;
        ob.u[i * 4 + 1] = f2bf(xv[i].y, &b); s += b;
        ob.u[i * 4 + 2] = f2bf(xv[i].z, &b); s += b;
        ob.u[i * 4 + 3] = f2bf(xv[i].w, &b); s += b;
    }
    // scatter into fragment order
    {
        const int mm = t >> 4, nn = t & 15;
        const int kchunk = tid >> 1;
        #pragma unroll
        for (int i = 0; i < 2; ++i) {
            const int qd = (tid * 2 + i) & 3;
            xf4[(size_t)((mm * 128 + kchunk) * 64 + qd * 16 + nn)] = ob.q[i];
        }
    }
    redg[tid] = s;

    // LoRA mid partials
    float pj[16];
    #pragma unroll
    for (int j = 0; j < 16; ++j) {
        const float4* ap = (const float4*)(loraA + (size_t)j * IN_F + tid * 16);
        float ps = 0.f;
        #pragma unroll
        for (int i = 0; i < 4; ++i) {
            float4 a = ap[i];
            ps += a.x * xv[i].x + a.y * xv[i].y + a.z * xv[i].z + a.w * xv[i].w;
        }
        pj[j] = ps;
    }
    #pragma unroll
    for (int j = 0; j < 16; ++j) {
        #pragma unroll
        for (int off = 32; off; off >>= 1) pj[j] += __shfl_down(pj[j], off);
    }
    if (lane == 0) {
        #pragma unroll
        for (int j = 0; j < 16; ++j) redm[wv][j] = pj[j];
    }
    __syncthreads();
    if (tid < NG) {
        float g = 0.f;
        #pragma unroll
        for (int i = 0; i < 8; ++i) g += redg[tid * 8 + i];
        xsumT[tid * TOKENS + t] = g;
    }
    if (tid < 16)
        midT[tid * TOKENS + t] = redm[0][tid] + redm[1][tid] + redm[2][tid] + redm[3][tid];
}

// ---------------------------------------------------------------------------
// K2: GPTQ-dequant GEMM + in-LDS split-K reduce + LoRA epilogue.
// Grid = 344 blocks (one per 32-col slice); block 512 = 8 waves =
// (mh 0/1: which 32 tokens) x (kseg 0..3: which 8 groups). Wave = 2 M-tiles
// x 32 cols x 8 groups — r8's proven shape (each dequanted word feeds 2
// MFMAs). Zero atomics; ONE barrier; outputs stored once, coalesced.
// B ring depth 3 (HBM/L3 latency); A/XS/S/Z depth 2 (L2-hot).
// LDS partials padded to row stride 34 floats -> <=2-way conflicts (free).
// ---------------------------------------------------------------------------
#define PROW 34
#define PIDX(mhv, ksv, tlv) (((mhv) * 4 + (ksv)) * (32 * PROW) + (tlv) * PROW)

#define LOADB(sb, g) do {                                                       \
    _Pragma("unroll")                                                           \
    for (int ks = 0; ks < 4; ++ks)                                              \
        _Pragma("unroll")                                                       \
        for (int nh = 0; nh < 2; ++nh)                                          \
            B[sb][ks * 2 + nh] =                                                \
                qwc[(size_t)((g) * 16 + ks * 4 + quad) * OUT_F + nh * 16];      \
} while (0)

#define LOADA(sa, g) do {                                                       \
    _Pragma("unroll")                                                           \
    for (int mt = 0; mt < 2; ++mt)                                              \
        _Pragma("unroll")                                                       \
        for (int ks = 0; ks < 4; ++ks)                                          \
            A[sa][mt * 4 + ks] =                                                \
                xf4[(size_t)((((mh * 2 + mt) * 128 + (g) * 4 + ks) * 64)) + lane];\
    _Pragma("unroll")                                                           \
    for (int mt = 0; mt < 2; ++mt)                                              \
        XS[sa][mt] = *(const float4*)(xsumT + (g) * 64 +                        \
                                      (mh * 2 + mt) * 16 + quad * 4);           \
    _Pragma("unroll")                                                           \
    for (int nh = 0; nh < 2; ++nh) {                                            \
        S[sa][nh] = scales[(size_t)(g) * OUT_F + col0 + nh * 16 + n];           \
        Z[sa][nh] = qz[(size_t)(g) * ZCOLS + ((col0 + nh * 16 + n) >> 3)];      \
    }                                                                           \
} while (0)

#define COMPUTEG(sa, sb) do {                                                   \
    float4v accg[2][2];                                                         \
    _Pragma("unroll")                                                           \
    for (int mt = 0; mt < 2; ++mt)                                              \
        _Pragma("unroll")                                                       \
        for (int nh = 0; nh < 2; ++nh)                                          \
            accg[mt][nh] = (float4v){0.f, 0.f, 0.f, 0.f};                       \
    _Pragma("unroll")                                                           \
    for (int ks = 0; ks < 4; ++ks) {                                            \
        union { uint4 u; short8 s; } af0, af1;                                  \
        af0.u = A[sa][ks];                                                      \
        af1.u = A[sa][4 + ks];                                                  \
        _Pragma("unroll")                                                       \
        for (int nh = 0; nh < 2; ++nh) {                                        \
            uint32_t q  = B[sb][ks * 2 + nh];                                   \
            uint32_t lo = q & 0x0F0F0F0Fu;                                      \
            uint32_t hi = (q >> 4) & 0x0F0F0F0Fu;                               \
            union { uint32_t u32[4]; short8 s8; } bf;                           \
            _Pragma("unroll")                                                   \
            for (int i = 0; i < 4; ++i)                                         \
                bf.u32[i] = __builtin_amdgcn_perm(hi, lo,                       \
                                0x0C040C00u + i * 0x00010001u) | 0x43004300u;   \
            accg[0][nh] = __builtin_amdgcn_mfma_f32_16x16x32_bf16(af0.s, bf.s8, \
                                                            accg[0][nh], 0, 0, 0);\
            accg[1][nh] = __builtin_amdgcn_mfma_f32_16x16x32_bf16(af1.s, bf.s8, \
                                                            accg[1][nh], 0, 0, 0);\
        }                                                                       \
    }                                                                           \
    _Pragma("unroll")                                                           \
    for (int nh = 0; nh < 2; ++nh) {                                            \
        const float zoff = (float)(((Z[sa][nh] >>                               \
                        (((col0 + nh * 16 + n) & 7) * 4)) & 0xFu) + 129u);      \
        const float scl = S[sa][nh];                                            \
        _Pragma("unroll")                                                       \
        for (int mt = 0; mt < 2; ++mt) {                                        \
            const float xr[4] = {XS[sa][mt].x, XS[sa][mt].y,                    \
                                 XS[sa][mt].z, XS[sa][mt].w};                   \
            _Pragma("unroll")                                                   \
            for (int r = 0; r < 4; ++r)                                         \
                acc[mt][nh][r] = fmaf(scl, fmaf(-zoff, xr[r],                   \
                                      accg[mt][nh][r]), acc[mt][nh][r]);        \
        }                                                                       \
    }                                                                           \
} while (0)

__global__ __launch_bounds__(512, 3) void main_kernel(
        const uint32_t* __restrict__ qw,
        const uint32_t* __restrict__ qz,
        const float* __restrict__ scales,
        const uint4* __restrict__ xf4,
        const float* __restrict__ xsumT,
        const float* __restrict__ midT,
        const float* __restrict__ loraB,
        float* __restrict__ out) {
    __shared__ float part[2 * 4 * 32 * PROW];   // 34816 B

    const int tid  = threadIdx.x;
    const int wv   = tid >> 6;
    const int lane = tid & 63;
    const int n    = lane & 15;
    const int quad = lane >> 4;
    const int mh   = wv >> 2;              // token half (32 tokens)
    const int kseg = wv & 3;               // 8-group K segment
    const int col0 = blockIdx.x * 32;
    const int g0   = kseg * GPK;

    const uint32_t* qwc = qw + col0 + n;

    float4v acc[2][2];
    #pragma unroll
    for (int mt = 0; mt < 2; ++mt)
        #pragma unroll
        for (int nh = 0; nh < 2; ++nh)
            acc[mt][nh] = (float4v){0.f, 0.f, 0.f, 0.f};

    uint4    A[2][8];
    uint32_t B[3][8];
    float4   XS[2][2];
    float    S[2][2];
    uint32_t Z[2][2];

    LOADB(0, g0); LOADB(1, g0 + 1); LOADB(2, g0 + 2);
    LOADA(0, g0); LOADA(1, g0 + 1);
    #pragma unroll
    for (int gi = 0; gi < GPK; ++gi) {
        const int sb = gi % 3, sa = gi & 1;
        COMPUTEG(sa, sb);
        if (gi + 3 < GPK) LOADB(sb, g0 + gi + 3);   // folds at compile time
        if (gi + 2 < GPK) LOADA(sa, g0 + gi + 2);
    }

    // write partials to LDS: part[mh][kseg][t_local][col_local]
    {
        float* pb = part + PIDX(mh, kseg, 0);
        #pragma unroll
        for (int mt = 0; mt < 2; ++mt)
            #pragma unroll
            for (int nh = 0; nh < 2; ++nh)
                #pragma unroll
                for (int r = 0; r < 4; ++r)
                    pb[(mt * 16 + quad * 4 + r) * PROW + nh * 16 + n] =
                        acc[mt][nh][r];
    }
    __syncthreads();   // the only barrier

    // reduce 4 ksegs + LoRA + store. Thread -> (mh', t_local, 4 cols).
    {
        const int emh = tid >> 8;          // 0/1
        const int rem = tid & 255;
        const int tl  = rem >> 3;          // 0..31
        const int c4  = (rem & 7) * 4;     // 0,4,...,28
        const int t   = emh * 32 + tl;

        float4 sum = *(const float4*)&part[PIDX(emh, 0, tl) + c4];
        #pragma unroll
        for (int ks = 1; ks < 4; ++ks) {
            const float4 p = *(const float4*)&part[PIDX(emh, ks, tl) + c4];
            sum.x += p.x; sum.y += p.y; sum.z += p.z; sum.w += p.w;
        }

        // LoRA: ls[c] = sum_j midT[j][t] * loraB[col][j]
        float m[16];
        #pragma unroll
        for (int j = 0; j < 16; ++j) m[j] = midT[j * TOKENS + t];
        float ls[4];
        #pragma unroll
        for (int c = 0; c < 4; ++c) {
            const float4* b4 = (const float4*)(loraB + (size_t)(col0 + c4 + c) * RANK);
            float a = 0.f;
            #pragma unroll
            for (int i = 0; i < 4; ++i) {
                float4 b = b4[i];
                a += b.x * m[i * 4 + 0] + b.y * m[i * 4 + 1]
                   + b.z * m[i * 4 + 2] + b.w * m[i * 4 + 3];
            }
            ls[c] = a;
        }

        float4 o;
        o.x = sum.x + LORA_SCALE * ls[0];
        o.y = sum.y + LORA_SCALE * ls[1];
        o.z = sum.z + LORA_SCALE * ls[2];
        o.w = sum.w + LORA_SCALE * ls[3];
        *(float4*)(out + (size_t)t * OUT_F + col0 + c4) = o;
    }
}

// ---------------------------------------------------------------------------
extern "C" void kernel_launch(void* const* d_in, const int* in_sizes, int n_in,
                              void* d_out, int out_size, void* d_ws, size_t ws_size,
                              hipStream_t stream) {
    const float*    x      = (const float*)d_in[0];
    const uint32_t* qw     = (const uint32_t*)d_in[1];
    const uint32_t* qz     = (const uint32_t*)d_in[2];
    const float*    scales = (const float*)d_in[3];
    const float*    loraA  = (const float*)d_in[4];
    const float*    loraB  = (const float*)d_in[5];
    float* out = (float*)d_out;

    // ws layout: xf [4][128][64] uint4 (512 KB) | xsumT [32][64] | midT [16][64]
    uint4* xf4   = (uint4*)d_ws;
    float* xsumT = (float*)((char*)d_ws + (size_t)TOKENS * IN_F * 2);
    float* midT  = xsumT + NG * TOKENS;

    prep_kernel<<<TOKENS, 256, 0, stream>>>(x, loraA, xf4, xsumT, midT);
    main_kernel<<<OUT_F / 32, 512, 0, stream>>>(qw, qz, scales, xf4, xsumT,
                                                midT, loraB, out);
}